// Round 11
// baseline (334.129 us; speedup 1.0000x reference)
//
#include <hip/hip_runtime.h>
#include <hip/hip_bf16.h>

#define B_TOTAL 131072
#define BLK 512
#define WIN 512
#define TILE 32

typedef __attribute__((ext_vector_type(8))) short bf16x8;
typedef __attribute__((ext_vector_type(4))) float f32x4;

__device__ inline short bf_cvt(float x) {
    __hip_bfloat16 h = __float2bfloat16(x);   // RNE
    return *reinterpret_cast<short*>(&h);
}
__device__ inline float bf2f(short s) {
    unsigned u = ((unsigned)(unsigned short)s) << 16;
    return __uint_as_float(u);
}
__device__ inline bf16x8 cvt8(float4 a, float4 b) {
    bf16x8 r;
    r[0] = bf_cvt(a.x); r[1] = bf_cvt(a.y); r[2] = bf_cvt(a.z); r[3] = bf_cvt(a.w);
    r[4] = bf_cvt(b.x); r[5] = bf_cvt(b.y); r[6] = bf_cvt(b.z); r[7] = bf_cvt(b.w);
    return r;
}

// Workgroup barrier ordering LDS (lgkm) only — no vmcnt drain.
__device__ inline void wg_barrier_lgkm() {
    asm volatile("s_waitcnt lgkmcnt(0)" ::: "memory");
    __builtin_amdgcn_s_barrier();
    asm volatile("" ::: "memory");
}

// XOR-swizzled element index into At (bf16 elems, row stride 1024, 32 rows).
__device__ inline int atx(int row, int kbf) {
    return (row * 1024 + kbf) ^ ((row & 7) << 3);
}

__global__ __launch_bounds__(BLK, 2) void nnue_seq_kernel(
    const float* __restrict__ accum,
    const float* __restrict__ us,
    const float* __restrict__ l1_w,
    const float* __restrict__ l1_b,
    const float* __restrict__ l2_w,
    const float* __restrict__ l2_b,
    const float* __restrict__ out_w,
    const float* __restrict__ out_b,
    const int*   __restrict__ psqt_indices,
    const int*   __restrict__ lsi,
    float*       __restrict__ out)
{
    __shared__ __align__(16) short At[TILE * 1024];     // 64 KB bf16 tile, swizzled
    __shared__ __align__(16) float w2t[16][8][32];      // 16 KB: [k][l][j2]
    __shared__ float w3s[8 * 32];                       // out_w
    __shared__ float b2s[8 * 32];                       // l2_b
    __shared__ float obs[8];                            // out_b
    __shared__ __align__(16) float psq[2][TILE][16];    // psqt fp32, parity
    __shared__ float uss[2][TILE];
    __shared__ int   lsis[2][TILE];
    __shared__ int   pis[2][TILE];
    __shared__ __align__(16) short l1y_all[8][TILE][16];// 8 KB bf16

    const int tid  = threadIdx.x;
    const int lane = tid & 63;
    const int wid  = tid >> 6;          // wave id == stack index l
    const int base = blockIdx.x * WIN;

    // ---- one-time LDS weight tables ----
    for (int i = tid; i < 4096; i += BLK) {
        int l_ = i >> 9, j2 = (i >> 4) & 31, k = i & 15;
        w2t[k][l_][j2] = l2_w[i];
    }
    for (int i = tid; i < 256; i += BLK) { w3s[i] = out_w[i]; b2s[i] = l2_b[i]; }
    if (tid < 8) obs[tid] = out_b[tid];

    const int jlow = lane & 15;
    const int g    = lane >> 4;

    // ---- persistent L1 weights for this wave's l (full K in regs) ----
    const float* wrow = l1_w + (((size_t)wid * 16 + jlow) << 10);
    bf16x8 wfrag[32];
    #pragma unroll
    for (int i = 0; i < 32; ++i) {
        const int kf = i * 32 + g * 8;
        wfrag[i] = cvt8(*(const float4*)(wrow + kf), *(const float4*)(wrow + kf + 4));
    }
    const float l1b = l1_b[wid * 16 + jlow];

    // ---- staging mapping: one (row, chunk8-column) per thread ----
    const int srow = tid >> 4;     // 0..31
    const int c8s  = tid & 15;     // 0..15
    const int prow = tid >> 2;     // psq row (tid<128)
    const int pq   = tid & 3;
    const int psf  = (pq < 2) ? (512 + 4 * pq) : (1032 + 4 * (pq - 2));

    float4 pfa[8], pfb[8], pfq;
    float usn = 0.f; int lsin = 0, pin = 0;

    auto issue_pf = [&](int tb) {
        const float* src = accum + (size_t)(base + tb + srow) * 1040;
        #pragma unroll
        for (int p = 0; p < 8; ++p) {
            const int sf = 8 * (c8s + 16 * p) + (p >= 4 ? 8 : 0);   // skip psqt gap
            pfa[p] = *(const float4*)(src + sf);
            pfb[p] = *(const float4*)(src + sf + 4);
        }
        if (tid < 128) {
            const float* s2 = accum + (size_t)(base + tb + prow) * 1040;
            pfq = *(const float4*)(s2 + psf);
        }
        if (tid < TILE) {
            lsin = lsi[base + tb + tid];
            usn  = us[base + tb + tid];
            pin  = psqt_indices[base + tb + tid];
        }
    };

    auto stage = [&](int par) {
        #pragma unroll
        for (int p = 0; p < 8; ++p)
            *(bf16x8*)&At[atx(srow, 8 * (c8s + 16 * p))] = cvt8(pfa[p], pfb[p]);
        if (tid < 128) *(float4*)&psq[par][prow][pq * 4] = pfq;
        if (tid < TILE) { lsis[par][tid] = lsin; uss[par][tid] = usn; pis[par][tid] = pin; }
    };

    issue_pf(0);

    for (int tb = 0; tb < WIN; tb += TILE) {
        const int par = (tb >> 5) & 1;
        stage(par);
        wg_barrier_lgkm();                         // At + aux[par] ready
        if (tb + TILE < WIN) issue_pf(tb + TILE);  // in flight across compute+epi

        // ---- L1 MFMA: this wave's l over both 16-sample groups, full K ----
        f32x4 acc0 = {0.f, 0.f, 0.f, 0.f};
        f32x4 acc1 = {0.f, 0.f, 0.f, 0.f};
        #pragma unroll
        for (int i = 0; i < 32; ++i) {
            const int kf = i * 32 + g * 8;
            bf16x8 a0 = *(const bf16x8*)&At[atx(jlow,      kf)];
            bf16x8 a1 = *(const bf16x8*)&At[atx(16 + jlow, kf)];
            acc0 = __builtin_amdgcn_mfma_f32_16x16x32_bf16(a0, wfrag[i], acc0, 0, 0, 0);
            acc1 = __builtin_amdgcn_mfma_f32_16x16x32_bf16(a1, wfrag[i], acc1, 0, 0, 0);
        }
        #pragma unroll
        for (int r = 0; r < 4; ++r) {
            float v0 = fminf(fmaxf(acc0[r] + l1b, 0.f), 1.f);
            float v1 = fminf(fmaxf(acc1[r] + l1b, 0.f), 1.f);
            l1y_all[wid][g * 4 + r][jlow]      = bf_cvt(v0);
            l1y_all[wid][16 + g * 4 + r][jlow] = bf_cvt(v1);
        }
        wg_barrier_lgkm();                         // l1y_all ready; At consumed

        // ---- fully parallel epilogue: 16 threads per sample ----
        {
            const int s  = tid >> 4;               // 0..31
            const int r2 = tid & 15;               // j2 rows r2, r2+16
            const int lE = lsis[par][s];

            bf16x8 y0 = *(const bf16x8*)&l1y_all[lE][s][0];
            bf16x8 y1 = *(const bf16x8*)&l1y_all[lE][s][8];
            float y[16];
            #pragma unroll
            for (int k = 0; k < 8; ++k) { y[k] = bf2f(y0[k]); y[8 + k] = bf2f(y1[k]); }

            float d0 = b2s[lE * 32 + r2];
            float d1 = b2s[lE * 32 + r2 + 16];
            #pragma unroll
            for (int k = 0; k < 16; ++k) {
                d0 += y[k] * w2t[k][lE][r2];
                d1 += y[k] * w2t[k][lE][r2 + 16];
            }
            d0 = fminf(fmaxf(d0, 0.f), 1.f);
            d1 = fminf(fmaxf(d1, 0.f), 1.f);
            float part = d0 * w3s[lE * 32 + r2] + d1 * w3s[lE * 32 + r2 + 16];
            part += __shfl_xor(part, 1);
            part += __shfl_xor(part, 2);
            part += __shfl_xor(part, 4);
            part += __shfl_xor(part, 8);

            if (r2 == 0) {
                const int pi = pis[par][s];
                const float wp = psq[par][s][pi];
                const float bp = psq[par][s][8 + pi];
                out[base + tb + s] = part + obs[lE] + (wp - bp) * (uss[par][s] - 0.5f);
            }
        }
        // WAR audit: next stage writes At (epilogue never reads At); l1y_all
        // rewritten only after next barrier-1 (all waves past this epilogue);
        // psq/uss/lsis/pis parity-buffered, reused two barriers later.
    }
}

extern "C" void kernel_launch(void* const* d_in, const int* in_sizes, int n_in,
                              void* d_out, int out_size, void* d_ws, size_t ws_size,
                              hipStream_t stream) {
    const float* accum = (const float*)d_in[0];
    const float* us    = (const float*)d_in[1];
    const float* l1_w  = (const float*)d_in[2];
    const float* l1_b  = (const float*)d_in[3];
    const float* l2_w  = (const float*)d_in[4];
    const float* l2_b  = (const float*)d_in[5];
    const float* out_w = (const float*)d_in[6];
    const float* out_b = (const float*)d_in[7];
    const int*   psqt  = (const int*)d_in[8];
    const int*   lsi   = (const int*)d_in[9];
    float* out = (float*)d_out;

    nnue_seq_kernel<<<B_TOTAL / WIN, BLK, 0, stream>>>(
        accum, us, l1_w, l1_b, l2_w, l2_b, out_w, out_b, psqt, lsi, out);
}

// Round 12
// 117.406 us; speedup vs baseline: 2.8459x; 2.8459x over previous
//
#include <hip/hip_runtime.h>
#include <hip/hip_bf16.h>

#define NCOUNT 8
#define B_TOTAL 131072
#define W_WIN 1024
#define BLK 256

typedef __attribute__((ext_vector_type(8))) short bf16x8;
typedef __attribute__((ext_vector_type(4))) float f32x4;
typedef __attribute__((ext_vector_type(16))) float f32x16;

__device__ inline short bf_cvt(float x) {
    __hip_bfloat16 h = __float2bfloat16(x);   // RNE
    return *reinterpret_cast<short*>(&h);
}
__device__ inline bf16x8 cvt8(float4 a, float4 b) {
    bf16x8 r;
    r[0] = bf_cvt(a.x); r[1] = bf_cvt(a.y); r[2] = bf_cvt(a.z); r[3] = bf_cvt(a.w);
    r[4] = bf_cvt(b.x); r[5] = bf_cvt(b.y); r[6] = bf_cvt(b.z); r[7] = bf_cvt(b.w);
    return r;
}

// Workgroup barrier ordering LDS (lgkm) only — no vmcnt drain (T4).
__device__ inline void wg_barrier_lgkm() {
    asm volatile("s_waitcnt lgkmcnt(0)" ::: "memory");
    __builtin_amdgcn_s_barrier();
    asm volatile("" ::: "memory");
}

// XOR-swizzled element index into At (bf16 elems, row stride 1024).
__device__ inline int atx(int row, int kbf) {
    return (row * 1024 + kbf) ^ ((row & 7) << 3);
}

__global__ __launch_bounds__(BLK, 2) void nnue_mfma_kernel(
    const float* __restrict__ accum,
    const float* __restrict__ us,
    const float* __restrict__ l1_w,
    const float* __restrict__ l1_b,
    const float* __restrict__ l2_w,
    const float* __restrict__ l2_b,
    const float* __restrict__ out_w,
    const float* __restrict__ out_b,
    const int*   __restrict__ psqt_indices,
    const int*   __restrict__ lsi,
    float*       __restrict__ out)
{
    __shared__ unsigned short list[W_WIN];              // window-local offsets (ascending)
    __shared__ int wsum[4];
    __shared__ __align__(16) short At[32 * 1024];       // 64 KB bf16 tile, swizzled
    __shared__ __align__(16) float psq[2][32][16];      // psqt floats, parity buf
    __shared__ __align__(16) f32x4 l1part[2][3][64];    // split-K partials
    __shared__ __align__(16) float l1y[2][16 * 20];     // per-group activation exchange
    __shared__ float epiw[64];                          // [0:32) l2_b, [32:64) out_w

    const int l    = blockIdx.y;
    const int base = blockIdx.x * W_WIN;
    const int tid  = threadIdx.x;
    const int lane = tid & 63;
    const int wid  = tid >> 6;

    const int jlow  = lane & 15;
    const int g     = lane >> 4;
    const int col32 = lane & 31;
    const int h     = lane >> 5;

    // ---- issue lsi loads first (oldest in vmcnt queue) ----
    int myl[4];
    #pragma unroll
    for (int it = 0; it < 4; ++it) myl[it] = lsi[base + it * BLK + tid];

    // ---- issue weight loads (latency hides under compaction) ----
    const float* wrow = l1_w + (((size_t)l * 16 + jlow) << 10);
    float4 wr0[8], wr1[8];
    #pragma unroll
    for (int i = 0; i < 8; ++i) {
        const int kf = (wid * 8 + i) * 32 + g * 8;
        wr0[i] = *(const float4*)(wrow + kf);
        wr1[i] = *(const float4*)(wrow + kf + 4);
    }
    const float* w2row = l2_w + ((size_t)l * 32 + col32) * 16 + h * 8;
    const float4 w2a = *(const float4*)(w2row);
    const float4 w2b = *(const float4*)(w2row + 4);
    const float l1bias = l1_b[l * 16 + jlow];
    const float outb   = out_b[l];

    if (tid < 64)
        epiw[tid] = (tid < 32) ? l2_b[l * 32 + tid] : out_w[l * 32 + (tid - 32)];

    // ---- ballot compaction: ascending, no atomics ----
    int n = 0;
    #pragma unroll
    for (int it = 0; it < 4; ++it) {
        const bool m = (myl[it] == l);
        const unsigned long long mask = __ballot(m);
        const int cnt_w = __popcll(mask);
        const int pos_w = __popcll(mask & ((1ull << lane) - 1ull));
        if (lane == 0) wsum[wid] = cnt_w;
        wg_barrier_lgkm();
        int pre = 0;
        #pragma unroll
        for (int w = 0; w < 4; ++w) if (w < wid) pre += wsum[w];
        const int itot = wsum[0] + wsum[1] + wsum[2] + wsum[3];
        if (m) list[n + pre + pos_w] = (unsigned short)(it * BLK + tid);
        n += itot;
        wg_barrier_lgkm();                       // wsum/list WAR + visibility
    }
    if (n == 0) return;

    // ---- cvt persistent weights (drains weight loads) ----
    bf16x8 wfrag[8];
    #pragma unroll
    for (int i = 0; i < 8; ++i) wfrag[i] = cvt8(wr0[i], wr1[i]);
    const bf16x8 w2frag = cvt8(w2a, w2b);

    const int srow  = tid >> 5;   // rows 8*rr + srow, rr=0..3
    const int scol8 = tid & 31;   // 8-float chunk lane
    const int pr    = tid >> 2;   // psq staging row (tid<128: 0..31)
    const int ppart = tid & 3;
    const int psf   = (ppart < 2) ? (512 + 4 * ppart) : (1032 + 4 * (ppart - 2));

    // ---- register prefetch (one 32-row tile in flight) ----
    float4 pfa[16], pfb[16], pfq;
    float usn = 0.f, usc; int pin = 0, pic;

    auto issue_pf = [&](int tbn) {
        #pragma unroll
        for (int rr = 0; rr < 4; ++rr) {
            const int mi = tbn + 8 * rr + srow;
            const int s  = base + list[mi < n ? mi : n - 1];
            const float* src = accum + (size_t)s * 1040;
            #pragma unroll
            for (int p = 0; p < 4; ++p) {
                const int sf = 8 * (scol8 + 32 * p) + (p >= 2 ? 8 : 0);
                pfa[rr * 4 + p] = *(const float4*)(src + sf);
                pfb[rr * 4 + p] = *(const float4*)(src + sf + 4);
            }
        }
        if (tid < 128) {
            const int mi = tbn + pr;
            const float* src = accum + (size_t)(base + list[mi < n ? mi : n - 1]) * 1040;
            pfq = *(const float4*)(src + psf);
        }
        if (lane < 16 && wid < 2) {
            const int mi = tbn + wid * 16 + jlow;
            const int s  = base + list[mi < n ? mi : n - 1];
            usn = us[s];
            pin = psqt_indices[s];
        }
    };

    auto stage = [&](int par) {
        #pragma unroll
        for (int rr = 0; rr < 4; ++rr) {
            const int row = 8 * rr + srow;
            #pragma unroll
            for (int p = 0; p < 4; ++p)
                *(bf16x8*)&At[atx(row, 8 * (scol8 + 32 * p))] =
                    cvt8(pfa[rr * 4 + p], pfb[rr * 4 + p]);
        }
        if (tid < 128) *(float4*)&psq[par][pr][ppart * 4] = pfq;
    };

    issue_pf(0);

    int par = 0;
    for (int tb = 0; tb < n; tb += 32, par ^= 1) {
        stage(par);
        wg_barrier_lgkm();                     // At + psq[par] ready (no vmcnt drain)
        usc = usn; pic = pin;
        if (tb + 32 < n) issue_pf(tb + 32);    // stays in flight across compute+epi

        // ---- split-K MFMA: two 16-sample groups per wave ----
        f32x4 a0 = {0.f, 0.f, 0.f, 0.f};
        f32x4 a1 = {0.f, 0.f, 0.f, 0.f};
        #pragma unroll
        for (int i = 0; i < 8; ++i) {
            const int kf = (wid * 8 + i) * 32 + g * 8;
            bf16x8 f0 = *(const bf16x8*)&At[atx(jlow,      kf)];
            bf16x8 f1 = *(const bf16x8*)&At[atx(jlow + 16, kf)];
            a0 = __builtin_amdgcn_mfma_f32_16x16x32_bf16(f0, wfrag[i], a0, 0, 0, 0);
            a1 = __builtin_amdgcn_mfma_f32_16x16x32_bf16(f1, wfrag[i], a1, 0, 0, 0);
        }
        if (wid != 0) l1part[0][wid - 1][lane] = a0;                // g0: waves 1,2,3
        if (wid != 1) l1part[1][wid == 0 ? 0 : wid - 1][lane] = a1; // g1: waves 0,2,3
        wg_barrier_lgkm();                     // l1part ready; At consumed

        // ---- dual parallel epilogue: wave0 -> group0, wave1 -> group1 ----
        if (wid < 2) {
            const int grp = wid;
            const f32x4 own = (wid == 0) ? a0 : a1;
            const f32x4 t0 = l1part[grp][0][lane];
            const f32x4 t1 = l1part[grp][1][lane];
            const f32x4 t2 = l1part[grp][2][lane];
            float* ly = l1y[grp];
            #pragma unroll
            for (int r = 0; r < 4; ++r) {
                float v = fminf(fmaxf(own[r] + t0[r] + t1[r] + t2[r] + l1bias, 0.f), 1.f);
                ly[(g * 4 + r) * 20 + jlow] = v;
            }
            __builtin_amdgcn_wave_barrier();
            asm volatile("s_waitcnt lgkmcnt(0)" ::: "memory");

            const float* lyr = ly + (col32 & 15) * 20 + h * 8;
            float4 y0 = *(const float4*)(lyr);
            float4 y1 = *(const float4*)(lyr + 4);
            const bf16x8 b2frag = cvt8(y0, y1);

            f32x16 acc2 = {};
            acc2 = __builtin_amdgcn_mfma_f32_32x32x16_bf16(w2frag, b2frag, acc2, 0, 0, 0);

            float partial = 0.f;
            #pragma unroll
            for (int r = 0; r < 16; ++r) {
                const int j2 = (r & 3) + 8 * (r >> 2) + 4 * h;
                float v = fminf(fmaxf(acc2[r] + epiw[j2], 0.f), 1.f);
                partial += v * epiw[32 + j2];
            }
            partial += __shfl_xor(partial, 32);

            const int mi = tb + grp * 16 + jlow;
            if (lane < 16 && mi < n) {
                const int s = base + list[mi];
                const float wp = psq[par][grp * 16 + jlow][pic];
                const float bp = psq[par][grp * 16 + jlow][8 + pic];
                out[s] = partial + outb + (wp - bp) * (usc - 0.5f);
            }
        }
        // Races audited (unchanged from R8): l1part WAR protected by next tile's
        // barrier-1; psq parity-double-buffered; epilogue never reads At.
    }
}

extern "C" void kernel_launch(void* const* d_in, const int* in_sizes, int n_in,
                              void* d_out, int out_size, void* d_ws, size_t ws_size,
                              hipStream_t stream) {
    const float* accum = (const float*)d_in[0];
    const float* us    = (const float*)d_in[1];
    const float* l1_w  = (const float*)d_in[2];
    const float* l1_b  = (const float*)d_in[3];
    const float* l2_w  = (const float*)d_in[4];
    const float* l2_b  = (const float*)d_in[5];
    const float* out_w = (const float*)d_in[6];
    const float* out_b = (const float*)d_in[7];
    const int*   psqt  = (const int*)d_in[8];
    const int*   lsi   = (const int*)d_in[9];
    float* out = (float*)d_out;

    dim3 grid(B_TOTAL / W_WIN, NCOUNT);
    nnue_mfma_kernel<<<grid, BLK, 0, stream>>>(
        accum, us, l1_w, l1_b, l2_w, l2_b, out_w, out_b, psqt, lsi, out);
}

// Round 13
// 108.069 us; speedup vs baseline: 3.0918x; 1.0864x over previous
//
#include <hip/hip_runtime.h>
#include <hip/hip_bf16.h>

#define NCOUNT 8
#define B_TOTAL 131072
#define W_WIN 1024
#define BLK 256

typedef __attribute__((ext_vector_type(8))) short bf16x8;
typedef __attribute__((ext_vector_type(4))) float f32x4;
typedef __attribute__((ext_vector_type(16))) float f32x16;

__device__ inline short bf_cvt(float x) {
    __hip_bfloat16 h = __float2bfloat16(x);   // RNE
    return *reinterpret_cast<short*>(&h);
}
__device__ inline bf16x8 cvt8(float4 a, float4 b) {
    bf16x8 r;
    r[0] = bf_cvt(a.x); r[1] = bf_cvt(a.y); r[2] = bf_cvt(a.z); r[3] = bf_cvt(a.w);
    r[4] = bf_cvt(b.x); r[5] = bf_cvt(b.y); r[6] = bf_cvt(b.z); r[7] = bf_cvt(b.w);
    return r;
}

// XOR-swizzled element index into At (bf16 elems, row stride 1024).
__device__ inline int atx(int row, int kbf) {
    return (row * 1024 + kbf) ^ ((row & 7) << 3);
}

__global__ __launch_bounds__(BLK, 2) void nnue_mfma_kernel(
    const float* __restrict__ accum,
    const float* __restrict__ us,
    const float* __restrict__ l1_w,
    const float* __restrict__ l1_b,
    const float* __restrict__ l2_w,
    const float* __restrict__ l2_b,
    const float* __restrict__ out_w,
    const float* __restrict__ out_b,
    const int*   __restrict__ psqt_indices,
    const int*   __restrict__ lsi,
    float*       __restrict__ out)
{
    __shared__ unsigned short list[W_WIN];              // window-local offsets
    __shared__ int cnt;
    __shared__ __align__(16) short At[32 * 1024];       // 64 KB bf16 tile, swizzled
    __shared__ __align__(16) float psq[2][32][16];      // psqt floats, parity buf
    __shared__ __align__(16) f32x4 l1part[2][3][64];    // split-K partials
    __shared__ __align__(16) float l1y[2][16 * 20];     // per-group activation exchange
    __shared__ float epiw[64];                          // [0:32) l2_b, [32:64) out_w

    const int l    = blockIdx.y;
    const int base = blockIdx.x * W_WIN;
    const int tid  = threadIdx.x;
    const int lane = tid & 63;
    const int wid  = tid >> 6;

    const int jlow  = lane & 15;
    const int g     = lane >> 4;
    const int col32 = lane & 31;
    const int h     = lane >> 5;

    // ---- pre-issue lsi loads (oldest in queue; compaction consumes them) ----
    int myl[4];
    #pragma unroll
    for (int it = 0; it < 4; ++it) myl[it] = lsi[base + it * BLK + tid];

    // ---- pre-issue weight loads: latency hides under compaction ----
    const float* wrow = l1_w + (((size_t)l * 16 + jlow) << 10);
    float4 wr0[8], wr1[8];
    #pragma unroll
    for (int i = 0; i < 8; ++i) {
        const int kf = (wid * 8 + i) * 32 + g * 8;
        wr0[i] = *(const float4*)(wrow + kf);
        wr1[i] = *(const float4*)(wrow + kf + 4);
    }
    const float* w2row = l2_w + ((size_t)l * 32 + col32) * 16 + h * 8;
    const float4 w2a = *(const float4*)(w2row);
    const float4 w2b = *(const float4*)(w2row + 4);
    const float l1bias = l1_b[l * 16 + jlow];
    const float outb   = out_b[l];

    // ---- compaction (atomic; HW coalesces to ~1 atomic/wave) ----
    if (tid == 0) cnt = 0;
    __syncthreads();
    #pragma unroll
    for (int it = 0; it < 4; ++it)
        if (myl[it] == l) list[atomicAdd(&cnt, 1)] = (unsigned short)(it * BLK + tid);
    if (tid < 64)
        epiw[tid] = (tid < 32) ? l2_b[l * 32 + tid] : out_w[l * 32 + (tid - 32)];
    __syncthreads();
    const int n = cnt;
    if (n == 0) return;

    // ---- cvt persistent weights (drains the pre-issued loads) ----
    bf16x8 wfrag[8];
    #pragma unroll
    for (int i = 0; i < 8; ++i) wfrag[i] = cvt8(wr0[i], wr1[i]);
    const bf16x8 w2frag = cvt8(w2a, w2b);

    const int srow  = tid >> 5;   // rows 8*rr + srow, rr=0..3
    const int scol8 = tid & 31;   // 8-float chunk lane
    const int pr    = tid >> 2;   // psq staging row (tid<128: 0..31)
    const int ppart = tid & 3;
    const int psf   = (ppart < 2) ? (512 + 4 * ppart) : (1032 + 4 * (ppart - 2));

    // ---- register prefetch (one 32-row tile in flight) ----
    float4 pfa[16], pfb[16], pfq;
    float usn = 0.f, usc; int pin = 0, pic;

    auto issue_pf = [&](int tbn) {
        #pragma unroll
        for (int rr = 0; rr < 4; ++rr) {
            const int mi = tbn + 8 * rr + srow;
            const int s  = base + list[mi < n ? mi : n - 1];
            const float* src = accum + (size_t)s * 1040;
            #pragma unroll
            for (int p = 0; p < 4; ++p) {
                const int sf = 8 * (scol8 + 32 * p) + (p >= 2 ? 8 : 0);
                pfa[rr * 4 + p] = *(const float4*)(src + sf);
                pfb[rr * 4 + p] = *(const float4*)(src + sf + 4);
            }
        }
        if (tid < 128) {
            const int mi = tbn + pr;
            const float* src = accum + (size_t)(base + list[mi < n ? mi : n - 1]) * 1040;
            pfq = *(const float4*)(src + psf);
        }
        if (lane < 16 && wid < 2) {
            const int mi = tbn + wid * 16 + jlow;
            const int s  = base + list[mi < n ? mi : n - 1];
            usn = us[s];
            pin = psqt_indices[s];
        }
    };

    auto stage = [&](int par) {
        #pragma unroll
        for (int rr = 0; rr < 4; ++rr) {
            const int row = 8 * rr + srow;
            #pragma unroll
            for (int p = 0; p < 4; ++p)
                *(bf16x8*)&At[atx(row, 8 * (scol8 + 32 * p))] =
                    cvt8(pfa[rr * 4 + p], pfb[rr * 4 + p]);
        }
        if (tid < 128) *(float4*)&psq[par][pr][ppart * 4] = pfq;
    };

    issue_pf(0);

    int par = 0;
    for (int tb = 0; tb < n; tb += 32, par ^= 1) {
        stage(par);
        __syncthreads();                       // At + psq[par] ready
        usc = usn; pic = pin;
        if (tb + 32 < n) issue_pf(tb + 32);    // stays in flight across compute+epi

        // ---- split-K MFMA: two 16-sample groups per wave ----
        f32x4 a0 = {0.f, 0.f, 0.f, 0.f};
        f32x4 a1 = {0.f, 0.f, 0.f, 0.f};
        #pragma unroll
        for (int i = 0; i < 8; ++i) {
            const int kf = (wid * 8 + i) * 32 + g * 8;
            bf16x8 f0 = *(const bf16x8*)&At[atx(jlow,      kf)];
            bf16x8 f1 = *(const bf16x8*)&At[atx(jlow + 16, kf)];
            a0 = __builtin_amdgcn_mfma_f32_16x16x32_bf16(f0, wfrag[i], a0, 0, 0, 0);
            a1 = __builtin_amdgcn_mfma_f32_16x16x32_bf16(f1, wfrag[i], a1, 0, 0, 0);
        }
        if (wid != 0) l1part[0][wid - 1][lane] = a0;                // g0: waves 1,2,3
        if (wid != 1) l1part[1][wid == 0 ? 0 : wid - 1][lane] = a1; // g1: waves 0,2,3
        __syncthreads();                       // l1part ready; At consumed

        // ---- dual parallel epilogue: wave0 -> group0, wave1 -> group1 ----
        if (wid < 2) {
            const int grp = wid;
            const f32x4 own = (wid == 0) ? a0 : a1;
            const f32x4 t0 = l1part[grp][0][lane];
            const f32x4 t1 = l1part[grp][1][lane];
            const f32x4 t2 = l1part[grp][2][lane];
            float* ly = l1y[grp];
            #pragma unroll
            for (int r = 0; r < 4; ++r) {
                float v = fminf(fmaxf(own[r] + t0[r] + t1[r] + t2[r] + l1bias, 0.f), 1.f);
                ly[(g * 4 + r) * 20 + jlow] = v;
            }
            __builtin_amdgcn_wave_barrier();
            asm volatile("s_waitcnt lgkmcnt(0)" ::: "memory");

            const float* lyr = ly + (col32 & 15) * 20 + h * 8;
            float4 y0 = *(const float4*)(lyr);
            float4 y1 = *(const float4*)(lyr + 4);
            const bf16x8 b2frag = cvt8(y0, y1);

            f32x16 acc2 = {};
            acc2 = __builtin_amdgcn_mfma_f32_32x32x16_bf16(w2frag, b2frag, acc2, 0, 0, 0);

            float partial = 0.f;
            #pragma unroll
            for (int r = 0; r < 16; ++r) {
                const int j2 = (r & 3) + 8 * (r >> 2) + 4 * h;
                float v = fminf(fmaxf(acc2[r] + epiw[j2], 0.f), 1.f);
                partial += v * epiw[32 + j2];
            }
            partial += __shfl_xor(partial, 32);

            const int mi = tb + grp * 16 + jlow;
            if (lane < 16 && mi < n) {
                const int s = base + list[mi];
                const float wp = psq[par][grp * 16 + jlow][pic];
                const float bp = psq[par][grp * 16 + jlow][8 + pic];
                out[s] = partial + outb + (wp - bp) * (usc - 0.5f);
            }
        }
        // Races audited: l1part WAR protected by next tile's first barrier;
        // psq parity-double-buffered; epilogue never reads At.
    }
}

extern "C" void kernel_launch(void* const* d_in, const int* in_sizes, int n_in,
                              void* d_out, int out_size, void* d_ws, size_t ws_size,
                              hipStream_t stream) {
    const float* accum = (const float*)d_in[0];
    const float* us    = (const float*)d_in[1];
    const float* l1_w  = (const float*)d_in[2];
    const float* l1_b  = (const float*)d_in[3];
    const float* l2_w  = (const float*)d_in[4];
    const float* l2_b  = (const float*)d_in[5];
    const float* out_w = (const float*)d_in[6];
    const float* out_b = (const float*)d_in[7];
    const int*   psqt  = (const int*)d_in[8];
    const int*   lsi   = (const int*)d_in[9];
    float* out = (float*)d_out;

    dim3 grid(B_TOTAL / W_WIN, NCOUNT);
    nnue_mfma_kernel<<<grid, BLK, 0, stream>>>(
        accum, us, l1_w, l1_b, l2_w, l2_b, out_w, out_b, psqt, lsi, out);
}